// Round 3
// baseline (736.732 us; speedup 1.0000x reference)
//
#include <hip/hip_runtime.h>
#include <math.h>

#define N_NODES 50000
#define N_EDGES 800000
#define N_GRAPHS 512
#define D 64
#define DE 32
#define NTILE (N_EDGES / 16)   // 50000 16-edge tiles
#define NB_SCAN 196            // ceil(50000/256)
#define NSTR 136               // NT LDS row stride (ushorts), 272B = 16B-aligned

// ---------------------------------------------------------------------------
// R12: edge_message restructured — no LDS, no scan, no shfl.
//  * wave = 4 CONSECUTIVE tiles (64 consecutive sorted edges); quad q owns
//    rows 4q..4q+3 of each tile. dst-sorted => long runs: per-quad register
//    run-length accumulation, 4 scalar atomics per dst-change (commutative,
//    other rows handled by other quads/waves).
//  * Tdst uint4 gather cached in registers, reloaded only on dst change
//    (~4x fewer dst gathers).
//  * B-fragments (W in MFMA frag layout, bf16-packed) precomputed once by
//    pack_W for BOTH node_transform (128 scalar loads/wave removed) and
//    edge_message; consumers do 2x dwordx4 loads per frag.
//  * bijective XCD swizzle (m204 formula) on edge grid: neighboring tiles
//    share Tdst rows + hout lines -> same-XCD L2.
//
// MFMA 16x16x32 bf16 fragment maps (m89/m120-verified):
//   A[m][k]: m = lane&15, k = (lane>>4)*8 + i
//   B[k][n]: n = lane&15, k = (lane>>4)*8 + i
//   C/D    : col n = lane&15, row m = (lane>>4)*4 + reg
// Edge column map (R11): column n16 of call jb holds channel j = 4*n16+jb,
// so a lane's 4 channels are one uint4 in T rows / one float4 in hout.
// ---------------------------------------------------------------------------

typedef __attribute__((ext_vector_type(8))) short short8;
typedef __attribute__((ext_vector_type(4))) float floatx4;
union Frag { short8 s; unsigned u[4]; };
union U4   { uint4 v; unsigned u[4]; };

__device__ inline unsigned pk_bf16(float lo, float hi) {
    unsigned a = __float_as_uint(lo);
    unsigned b = __float_as_uint(hi);
    a = (a + 0x7FFFu + ((a >> 16) & 1u)) >> 16;
    b = (b + 0x7FFFu + ((b >> 16) & 1u)) >> 16;
    return a | (b << 16);
}
__device__ inline unsigned short bf16_1(float v) {
    unsigned a = __float_as_uint(v);
    return (unsigned short)((a + 0x7FFFu + ((a >> 16) & 1u)) >> 16);
}
__device__ inline float upk(unsigned u16) { return __uint_as_float(u16 << 16); }

// ---------------- CSR build (once per call) --------------------------------
__global__ __launch_bounds__(256) void hist_kernel(
    const int* __restrict__ ei, int* __restrict__ deg)
{
    int e = blockIdx.x * 256 + threadIdx.x;
    atomicAdd(&deg[ei[N_EDGES + e]], 1);
}

__global__ __launch_bounds__(256) void scan1(
    const int* __restrict__ deg, int* __restrict__ off, int* __restrict__ tsum)
{
    __shared__ int s[256];
    int i = blockIdx.x * 256 + threadIdx.x;
    s[threadIdx.x] = (i < N_NODES) ? deg[i] : 0;
    __syncthreads();
    if (threadIdx.x == 0) {
        int run = 0;
        for (int k = 0; k < 256; ++k) { int t = s[k]; s[k] = run; run += t; }
        tsum[blockIdx.x] = run;
    }
    __syncthreads();
    if (i < N_NODES) off[i] = s[threadIdx.x];
}

__global__ __launch_bounds__(256) void scan2(int* __restrict__ tsum)
{
    __shared__ int s[256];
    int i = threadIdx.x;
    s[i] = (i < NB_SCAN) ? tsum[i] : 0;
    __syncthreads();
    if (i == 0) {
        int run = 0;
        for (int k = 0; k < NB_SCAN; ++k) { int t = s[k]; s[k] = run; run += t; }
    }
    __syncthreads();
    if (i < NB_SCAN) tsum[i] = s[i];
}

__global__ __launch_bounds__(256) void scan3(
    int* __restrict__ off, const int* __restrict__ tsum)
{
    int i = blockIdx.x * 256 + threadIdx.x;
    if (i < N_NODES) off[i] += tsum[blockIdx.x];
    if (i == N_NODES) off[i] = N_EDGES;
}

// scatter + ea pack in one pass: read side coalesced, write side random 64B
__global__ __launch_bounds__(256) void scatter_pack(
    const int* __restrict__ ei, const int* __restrict__ off,
    int* __restrict__ cnt, const float* __restrict__ ea,
    unsigned short* __restrict__ eaS,      // [N_EDGES][32] bf16, sorted order
    int2* __restrict__ sd_sorted)          // [N_EDGES] (src,dst), sorted
{
    int e = blockIdx.x * 256 + threadIdx.x;
    int s = ei[e];
    int d = ei[N_EDGES + e];
    int r = atomicAdd(&cnt[d], 1);
    int pos = off[d] + r;
    sd_sorted[pos] = make_int2(s, d);

    const float4* src4 = (const float4*)(ea + (size_t)e * 32);
    uint4* dst16 = (uint4*)(eaS + (size_t)pos * 32);
#pragma unroll
    for (int q = 0; q < 2; ++q) {
        float4 v0 = src4[4 * q + 0];
        float4 v1 = src4[4 * q + 1];
        float4 v2 = src4[4 * q + 2];
        float4 v3 = src4[4 * q + 3];
        uint4 o0;
        o0.x = pk_bf16(v0.x, v0.y); o0.y = pk_bf16(v0.z, v0.w);
        o0.z = pk_bf16(v1.x, v1.y); o0.w = pk_bf16(v1.z, v1.w);
        uint4 o1;
        o1.x = pk_bf16(v2.x, v2.y); o1.y = pk_bf16(v2.z, v2.w);
        o1.z = pk_bf16(v3.x, v3.y); o1.w = pk_bf16(v3.z, v3.w);
        dst16[2 * q + 0] = o0;
        dst16[2 * q + 1] = o1;
    }
}

// ---- B-fragment precompute (R12) ------------------------------------------
// WpkNT: [layer][part(2)][cbi(8)][lane(64)][2] uint4  (NT layout, j = col>>1)
// WpkE : [layer][jb(4)][lane(64)][2] uint4           (edge layout, j = 4n16+jb)
__global__ __launch_bounds__(256) void pack_W(
    const float* __restrict__ Wf1, const float* __restrict__ Ws1,
    const float* __restrict__ Wf2, const float* __restrict__ Ws2,
    uint4* __restrict__ WpkNT, uint4* __restrict__ WpkE)
{
    const int layer = blockIdx.y;
    const float* Wf = layer ? Wf2 : Wf1;
    const float* Ws = layer ? Ws2 : Ws1;
    const int i = blockIdx.x * 256 + threadIdx.x;   // 0..1279
    if (i < 1024) {
        const int p    = i >> 9;
        const int cbi  = (i >> 6) & 7;
        const int l    = i & 63;
        const int n16  = l & 15, quad = l >> 4, kc = quad * 8;
        const int col  = cbi * 16 + n16;
        const int j    = col >> 1;
        const float* Wsel = (col & 1) ? Ws : Wf;
        const int rbase = p * 64;
        U4 b0, b1;
#pragma unroll
        for (int pp = 0; pp < 4; ++pp) {
            b0.u[pp] = pk_bf16(Wsel[(rbase + kc + 2 * pp) * 64 + j],
                               Wsel[(rbase + kc + 2 * pp + 1) * 64 + j]);
            b1.u[pp] = pk_bf16(Wsel[(rbase + 32 + kc + 2 * pp) * 64 + j],
                               Wsel[(rbase + 32 + kc + 2 * pp + 1) * 64 + j]);
        }
        uint4* o = WpkNT + ((size_t)layer * 1024 + i) * 2;
        o[0] = b0.v; o[1] = b1.v;
    } else if (i < 1280) {
        const int k  = i - 1024;
        const int jb = k >> 6;
        const int l  = k & 63;
        const int n16 = l & 15, quad = l >> 4, c0 = quad * 8;
        const int j = n16 * 4 + jb;
        U4 bf_, bs_;
#pragma unroll
        for (int pp = 0; pp < 4; ++pp) {
            bf_.u[pp] = pk_bf16(Wf[(128 + c0 + 2 * pp) * 64 + j],
                                Wf[(128 + c0 + 2 * pp + 1) * 64 + j]);
            bs_.u[pp] = pk_bf16(Ws[(128 + c0 + 2 * pp) * 64 + j],
                                Ws[(128 + c0 + 2 * pp + 1) * 64 + j]);
        }
        uint4* o = WpkE + ((size_t)layer * 256 + k) * 2;
        o[0] = bf_.v; o[1] = bs_.v;
    }
}

// ---- node transform: Tdst/Tsrc = bf16[H @ W parts], (f,s)-pair layout -----
__global__ __launch_bounds__(256) void node_transform_mfma(
    const float* __restrict__ H,
    const float* __restrict__ bf,
    const float* __restrict__ bs,
    const uint4* __restrict__ Wpk,        // this layer's NT fragments
    unsigned short* __restrict__ Tdst,    // [N_NODES][128]
    unsigned short* __restrict__ Tsrc,    // [N_NODES][128]
    float* __restrict__ hinit)            // [N_NODES][64] <- copy of H
{
    __shared__ unsigned short lt[4][16 * NSTR];
    const int lane = threadIdx.x & 63;
    const int wid  = threadIdx.x >> 6;
    const int n16  = lane & 15;
    const int quad = lane >> 4;
    const int kc   = quad * 8;
    unsigned short* L = lt[wid];

    const int gid = blockIdx.x * 4 + wid;           // global wave id
    const int NW  = (N_NODES / 16) * 2;             // 6250 waves of work
    if (gid >= NW) return;
    const int ntile = gid >> 1;
    const int part  = gid & 1;                      // 0: dst-part, 1: src-part
    unsigned short* Tout = part ? Tsrc : Tdst;

    // A fragments once per wave
    const float* hrow = H + (size_t)(ntile * 16 + n16) * D;
    float4 q0 = *(const float4*)(hrow + kc);
    float4 q1 = *(const float4*)(hrow + kc + 4);
    float4 q2 = *(const float4*)(hrow + 32 + kc);
    float4 q3 = *(const float4*)(hrow + 32 + kc + 4);
    Frag a0, a1;
    a0.u[0] = pk_bf16(q0.x, q0.y); a0.u[1] = pk_bf16(q0.z, q0.w);
    a0.u[2] = pk_bf16(q1.x, q1.y); a0.u[3] = pk_bf16(q1.z, q1.w);
    a1.u[0] = pk_bf16(q2.x, q2.y); a1.u[1] = pk_bf16(q2.z, q2.w);
    a1.u[2] = pk_bf16(q3.x, q3.y); a1.u[3] = pk_bf16(q3.z, q3.w);

    // fused h-init copy (h = H), one writer per node tile
    if (part == 0) {
        float4* hp = (float4*)(hinit + (size_t)(ntile * 16 + n16) * D);
        hp[quad * 2]     = q0;
        hp[quad * 2 + 1] = q1;
        hp[8 + quad * 2] = q2;
        hp[9 + quad * 2] = q3;
    }

#pragma unroll
    for (int cbi = 0; cbi < 8; ++cbi) {
        const int col   = cbi * 16 + n16;    // 0..127 within this part
        const int sflag = col & 1;           // 0: f, 1: s
        const int j     = col >> 1;          // output channel 0..63

        Frag b0, b1;
        {
            const uint4* bp = Wpk + ((size_t)(part * 512 + cbi * 64 + lane)) * 2;
            *(uint4*)&b0 = bp[0];
            *(uint4*)&b1 = bp[1];
        }
        float bias = 0.0f;
        if (part == 0) bias = sflag ? bs[j] : bf[j];

        floatx4 acc = {bias, bias, bias, bias};
        acc = __builtin_amdgcn_mfma_f32_16x16x32_bf16(a0.s, b0.s, acc, 0, 0, 0);
        acc = __builtin_amdgcn_mfma_f32_16x16x32_bf16(a1.s, b1.s, acc, 0, 0, 0);

#pragma unroll
        for (int r = 0; r < 4; ++r)
            L[(quad * 4 + r) * NSTR + col] = bf16_1(acc[r]);
    }

    // wave-private tile -> coalesced stores (no barrier needed; same wave)
#pragma unroll
    for (int it = 0; it < 4; ++it) {
        const int node_l = it * 4 + quad;            // local node 0..15
        const int c8     = n16 * 8;                  // col group (8 ushorts)
        uint4 v = *(const uint4*)(L + node_l * NSTR + c8);
        *(uint4*)(Tout + (size_t)(ntile * 16 + node_l) * 128 + c8) = v;
    }
}

// ---- edge kernel: per-quad register run-length aggregation (R12) ----------
__global__ __launch_bounds__(256) void edge_message_mfma(
    const unsigned short* __restrict__ Tdst,  // [N_NODES][128] bf16
    const unsigned short* __restrict__ Tsrc,  // [N_NODES][128] bf16
    const unsigned short* __restrict__ eaS,   // [N_EDGES][32] bf16, sorted
    const int2* __restrict__ sd_sorted,       // [N_EDGES] (src,dst) sorted
    const uint4* __restrict__ WpkE,           // this layer's edge fragments
    float* __restrict__ hout)                 // [N_NODES][64], pre-init = hin
{
    const int lane = threadIdx.x & 63;
    const int wid  = threadIdx.x >> 6;
    const int n16  = lane & 15;
    const int quad = lane >> 4;
    const int c0   = quad * 8;

    Frag bfr[4], bsr[4];
#pragma unroll
    for (int jb = 0; jb < 4; ++jb) {
        *(uint4*)&bfr[jb] = WpkE[((size_t)(jb * 64 + lane)) * 2 + 0];
        *(uint4*)&bsr[jb] = WpkE[((size_t)(jb * 64 + lane)) * 2 + 1];
    }

    // bijective XCD swizzle (nwg = 3125, q = 390, rr = 5)
    const int nwg = gridDim.x;
    const int xcd = blockIdx.x & 7;
    const int idx = blockIdx.x >> 3;
    const int q   = nwg >> 3, rr = nwg & 7;
    const int sb  = (xcd < rr ? xcd * (q + 1) : rr * (q + 1) + (xcd - rr) * q) + idx;
    const int t0  = (sb * 4 + wid) * 4;      // first of 4 consecutive tiles

    const floatx4 zero = {0.0f, 0.0f, 0.0f, 0.0f};

    // per-quad run-length state
    int   cur_d = -1;
    U4    dreg; dreg.v = make_uint4(0u, 0u, 0u, 0u);
    float acc0 = 0.f, acc1 = 0.f, acc2 = 0.f, acc3 = 0.f;

#pragma unroll 1
    for (int tt = 0; tt < 4; ++tt) {
        const int p0 = (t0 + tt) * 16;

        // A fragment: one coalesced 16B bf16 load (sorted layout)
        Frag af;
        af.s = *(const short8*)(eaS + (size_t)(p0 + n16) * 32 + c0);

        floatx4 accf[4], accs[4];
#pragma unroll
        for (int jb = 0; jb < 4; ++jb) {
            accf[jb] = __builtin_amdgcn_mfma_f32_16x16x32_bf16(af.s, bfr[jb].s, zero, 0, 0, 0);
            accs[jb] = __builtin_amdgcn_mfma_f32_16x16x32_bf16(af.s, bsr[jb].s, zero, 0, 0, 0);
        }

        const int2* sdq = sd_sorted + p0 + quad * 4;  // quad-uniform rows

#pragma unroll
        for (int r = 0; r < 4; ++r) {
            const int2 sdm = sdq[r];                  // 16-lane broadcast load
            U4 s4;
            s4.v = *(const uint4*)(Tsrc + (size_t)sdm.x * 128 + n16 * 8);
            const int dv = sdm.y;
            if (dv != cur_d) {
                if (cur_d >= 0) {
                    float* hp = hout + (size_t)cur_d * D + n16 * 4;
                    atomicAdd(hp + 0, acc0);
                    atomicAdd(hp + 1, acc1);
                    atomicAdd(hp + 2, acc2);
                    atomicAdd(hp + 3, acc3);
                }
                cur_d = dv;
                dreg.v = *(const uint4*)(Tdst + (size_t)dv * 128 + n16 * 8);
                acc0 = acc1 = acc2 = acc3 = 0.f;
            }
#pragma unroll
            for (int jb = 0; jb < 4; ++jb) {
                unsigned d2 = dreg.u[jb];
                unsigned s2 = s4.u[jb];
                float vf = accf[jb][r] + upk(d2 & 0xFFFFu) + upk(s2 & 0xFFFFu);
                float vs = accs[jb][r] + upk(d2 >> 16) + upk(s2 >> 16);
                float sig = __builtin_amdgcn_rcpf(1.0f + __expf(-vf));
                float spl = fmaxf(vs, 0.0f) + __logf(1.0f + __expf(-fabsf(vs)));
                float msg = sig * spl;
                if      (jb == 0) acc0 += msg;
                else if (jb == 1) acc1 += msg;
                else if (jb == 2) acc2 += msg;
                else              acc3 += msg;
            }
        }
    }
    // final flush (cur_d always valid here)
    {
        float* hp = hout + (size_t)cur_d * D + n16 * 4;
        atomicAdd(hp + 0, acc0);
        atomicAdd(hp + 1, acc1);
        atomicAdd(hp + 2, acc2);
        atomicAdd(hp + 3, acc3);
    }
}

// segment_sum(h, batch) into pooled[N_GRAPHS][64]
// sorted batch -> run-length accumulate 16 nodes per wave
__global__ __launch_bounds__(256) void pool_kernel(
    const float* __restrict__ h,
    const int* __restrict__ batch,
    float* __restrict__ pooled)
{
    const int lane = threadIdx.x & 63;
    const int wid  = threadIdx.x >> 6;
    const int w = blockIdx.x * 4 + wid;
    const int n0 = w * 16;
    if (n0 >= N_NODES) return;
    const int nend = (n0 + 16 < N_NODES) ? (n0 + 16) : N_NODES;

    int cur = batch[n0];
    float acc = 0.0f;
    for (int n = n0; n < nend; ++n) {
        int b = batch[n];                      // wave-uniform scalar load
        float v = h[(size_t)n * D + lane];
        if (b != cur) {
            atomicAdd(&pooled[(size_t)cur * D + lane], acc);
            cur = b; acc = v;
        } else {
            acc += v;
        }
    }
    atomicAdd(&pooled[(size_t)cur * D + lane], acc);
}

__global__ __launch_bounds__(256) void out_kernel(
    const float* __restrict__ pooled,
    const float* __restrict__ Wout,
    const float* __restrict__ bout,
    float* __restrict__ out)
{
    const int g = blockIdx.x * blockDim.x + threadIdx.x;
    if (g >= N_GRAPHS) return;
    float acc = bout[0];
#pragma unroll
    for (int j = 0; j < D; ++j) acc = fmaf(pooled[(size_t)g * D + j], Wout[j], acc);
    out[g] = acc;
}

extern "C" void kernel_launch(void* const* d_in, const int* in_sizes, int n_in,
                              void* d_out, int out_size, void* d_ws, size_t ws_size,
                              hipStream_t stream) {
    const float* x     = (const float*)d_in[0];
    const int*   ei    = (const int*)  d_in[1];
    const float* ea    = (const float*)d_in[2];
    const int*   batch = (const int*)  d_in[3];
    const float* Wf1   = (const float*)d_in[4];
    const float* bf1   = (const float*)d_in[5];
    const float* Ws1   = (const float*)d_in[6];
    const float* bs1   = (const float*)d_in[7];
    const float* Wf2   = (const float*)d_in[8];
    const float* bf2   = (const float*)d_in[9];
    const float* Ws2   = (const float*)d_in[10];
    const float* bs2   = (const float*)d_in[11];
    const float* Wout  = (const float*)d_in[12];
    const float* bout  = (const float*)d_in[13];
    float* out = (float*)d_out;

    // workspace carve (~110 MB)
    char* base = (char*)d_ws;
    size_t o = 0;
    unsigned short* Tdst = (unsigned short*)(base + o); o += (size_t)N_NODES * 128 * 2;
    unsigned short* Tsrc = (unsigned short*)(base + o); o += (size_t)N_NODES * 128 * 2;
    unsigned short* eaS  = (unsigned short*)(base + o); o += (size_t)N_EDGES * 32 * 2;
    float* h1     = (float*)(base + o); o += (size_t)N_NODES * D * 4;
    float* h2     = (float*)(base + o); o += (size_t)N_NODES * D * 4;
    float* pooled = (float*)(base + o); o += (size_t)N_GRAPHS * D * 4;
    int* deg  = (int*)(base + o); o += (size_t)N_NODES * 4;
    int* off  = (int*)(base + o); o += (size_t)(N_NODES + 1) * 4;
    int* tsum = (int*)(base + o); o += 256 * 4;
    int2* sd_sorted = (int2*)(base + o); o += (size_t)N_EDGES * 8;
    uint4* WpkNT = (uint4*)(base + o); o += (size_t)2 * 1024 * 2 * 16;
    uint4* WpkE  = (uint4*)(base + o); o += (size_t)2 * 256 * 2 * 16;

    // ---- W fragment pack (both layers, both layouts) ----
    pack_W<<<dim3(5, 2), 256, 0, stream>>>(Wf1, Ws1, Wf2, Ws2, WpkNT, WpkE);

    // ---- CSR build + fused ea pack ----
    hipMemsetAsync(deg, 0, (size_t)N_NODES * 4, stream);
    hist_kernel<<<N_EDGES / 256, 256, 0, stream>>>(ei, deg);
    scan1<<<NB_SCAN, 256, 0, stream>>>(deg, off, tsum);
    scan2<<<1, 256, 0, stream>>>(tsum);
    scan3<<<NB_SCAN, 256, 0, stream>>>(off, tsum);
    hipMemsetAsync(deg, 0, (size_t)N_NODES * 4, stream);
    scatter_pack<<<N_EDGES / 256, 256, 0, stream>>>(ei, off, deg, ea, eaS, sd_sorted);

    // ---- layer 1 ----  (node_transform also writes h1 = x)
    node_transform_mfma<<<1563, 256, 0, stream>>>(x, bf1, bs1, WpkNT, Tdst, Tsrc, h1);
    edge_message_mfma<<<3125, 256, 0, stream>>>(Tdst, Tsrc, eaS, sd_sorted,
                                                WpkE, h1);

    // ---- layer 2 ----  (node_transform also writes h2 = h1)
    node_transform_mfma<<<1563, 256, 0, stream>>>(h1, bf2, bs2, WpkNT + 2048, Tdst, Tsrc, h2);
    edge_message_mfma<<<3125, 256, 0, stream>>>(Tdst, Tsrc, eaS, sd_sorted,
                                                WpkE + 512, h2);

    // ---- pool + out ----
    hipMemsetAsync(pooled, 0, (size_t)N_GRAPHS * D * 4, stream);
    pool_kernel<<<782, 256, 0, stream>>>(h2, batch, pooled);
    out_kernel<<<2, 256, 0, stream>>>(pooled, Wout, bout, out);
}

// Round 4
// 513.124 us; speedup vs baseline: 1.4358x; 1.4358x over previous
//
#include <hip/hip_runtime.h>
#include <math.h>

#define N_NODES 50000
#define N_EDGES 800000
#define N_GRAPHS 512
#define D 64
#define DE 32
#define NTILE (N_EDGES / 16)   // 50000 16-edge tiles
#define NB_SCAN 196            // ceil(50000/256)
#define NSTR 136               // NT LDS row stride (ushorts), 272B = 16B-aligned

// ---------------------------------------------------------------------------
// R13: R12's strided quad-ownership chopped dst runs every 4 edges ->
// 740K atomic flushes (WRITE_SIZE 205MB), dur 217us. Fix: permute the MFMA
// A-row->edge mapping so quad q owns 16 CONSECUTIVE sorted edges:
//   A row m of the tt-th MFMA  <-  edge  base + 16*(m>>2) + (m&3) + 4*tt
// Then C/D row m=4q+r of MFMA tt = edge base + 16q + 4tt + r, i.e. quad q
// processes edges base+16q .. base+16q+15 IN ORDER as (tt,r) advances.
// Register run-length aggregation + dst-register cache now see full runs
// (avg len 16): ~2 flushes / 2 dst gathers per 16 edges. No LDS, no scan,
// no shfl/readlane in the edge kernel at all.
//
// MFMA 16x16x32 bf16 fragment maps (m89/m120-verified):
//   A[m][k]: m = lane&15, k = (lane>>4)*8 + i
//   B[k][n]: n = lane&15, k = (lane>>4)*8 + i
//   C/D    : col n = lane&15, row m = (lane>>4)*4 + reg
// Edge column map (R11): column n16 of call jb holds channel j = 4*n16+jb,
// so a lane's 4 channels are one uint4 in T rows / one float4 in hout.
// ---------------------------------------------------------------------------

typedef __attribute__((ext_vector_type(8))) short short8;
typedef __attribute__((ext_vector_type(4))) float floatx4;
union Frag { short8 s; unsigned u[4]; };
union U4   { uint4 v; unsigned u[4]; };

__device__ inline unsigned pk_bf16(float lo, float hi) {
    unsigned a = __float_as_uint(lo);
    unsigned b = __float_as_uint(hi);
    a = (a + 0x7FFFu + ((a >> 16) & 1u)) >> 16;
    b = (b + 0x7FFFu + ((b >> 16) & 1u)) >> 16;
    return a | (b << 16);
}
__device__ inline unsigned short bf16_1(float v) {
    unsigned a = __float_as_uint(v);
    return (unsigned short)((a + 0x7FFFu + ((a >> 16) & 1u)) >> 16);
}
__device__ inline float upk(unsigned u16) { return __uint_as_float(u16 << 16); }

// ---------------- CSR build (once per call) --------------------------------
__global__ __launch_bounds__(256) void hist_kernel(
    const int* __restrict__ ei, int* __restrict__ deg)
{
    int e = blockIdx.x * 256 + threadIdx.x;
    atomicAdd(&deg[ei[N_EDGES + e]], 1);
}

__global__ __launch_bounds__(256) void scan1(
    const int* __restrict__ deg, int* __restrict__ off, int* __restrict__ tsum)
{
    __shared__ int s[256];
    int i = blockIdx.x * 256 + threadIdx.x;
    s[threadIdx.x] = (i < N_NODES) ? deg[i] : 0;
    __syncthreads();
    if (threadIdx.x == 0) {
        int run = 0;
        for (int k = 0; k < 256; ++k) { int t = s[k]; s[k] = run; run += t; }
        tsum[blockIdx.x] = run;
    }
    __syncthreads();
    if (i < N_NODES) off[i] = s[threadIdx.x];
}

__global__ __launch_bounds__(256) void scan2(int* __restrict__ tsum)
{
    __shared__ int s[256];
    int i = threadIdx.x;
    s[i] = (i < NB_SCAN) ? tsum[i] : 0;
    __syncthreads();
    if (i == 0) {
        int run = 0;
        for (int k = 0; k < NB_SCAN; ++k) { int t = s[k]; s[k] = run; run += t; }
    }
    __syncthreads();
    if (i < NB_SCAN) tsum[i] = s[i];
}

__global__ __launch_bounds__(256) void scan3(
    int* __restrict__ off, const int* __restrict__ tsum)
{
    int i = blockIdx.x * 256 + threadIdx.x;
    if (i < N_NODES) off[i] += tsum[blockIdx.x];
    if (i == N_NODES) off[i] = N_EDGES;
}

// scatter + ea pack in one pass: read side coalesced, write side random 64B
__global__ __launch_bounds__(256) void scatter_pack(
    const int* __restrict__ ei, const int* __restrict__ off,
    int* __restrict__ cnt, const float* __restrict__ ea,
    unsigned short* __restrict__ eaS,      // [N_EDGES][32] bf16, sorted order
    int2* __restrict__ sd_sorted)          // [N_EDGES] (src,dst), sorted
{
    int e = blockIdx.x * 256 + threadIdx.x;
    int s = ei[e];
    int d = ei[N_EDGES + e];
    int r = atomicAdd(&cnt[d], 1);
    int pos = off[d] + r;
    sd_sorted[pos] = make_int2(s, d);

    const float4* src4 = (const float4*)(ea + (size_t)e * 32);
    uint4* dst16 = (uint4*)(eaS + (size_t)pos * 32);
#pragma unroll
    for (int q = 0; q < 2; ++q) {
        float4 v0 = src4[4 * q + 0];
        float4 v1 = src4[4 * q + 1];
        float4 v2 = src4[4 * q + 2];
        float4 v3 = src4[4 * q + 3];
        uint4 o0;
        o0.x = pk_bf16(v0.x, v0.y); o0.y = pk_bf16(v0.z, v0.w);
        o0.z = pk_bf16(v1.x, v1.y); o0.w = pk_bf16(v1.z, v1.w);
        uint4 o1;
        o1.x = pk_bf16(v2.x, v2.y); o1.y = pk_bf16(v2.z, v2.w);
        o1.z = pk_bf16(v3.x, v3.y); o1.w = pk_bf16(v3.z, v3.w);
        dst16[2 * q + 0] = o0;
        dst16[2 * q + 1] = o1;
    }
}

// ---- B-fragment precompute (R12) ------------------------------------------
// WpkNT: [layer][part(2)][cbi(8)][lane(64)][2] uint4  (NT layout, j = col>>1)
// WpkE : [layer][jb(4)][lane(64)][2] uint4           (edge layout, j = 4n16+jb)
__global__ __launch_bounds__(256) void pack_W(
    const float* __restrict__ Wf1, const float* __restrict__ Ws1,
    const float* __restrict__ Wf2, const float* __restrict__ Ws2,
    uint4* __restrict__ WpkNT, uint4* __restrict__ WpkE)
{
    const int layer = blockIdx.y;
    const float* Wf = layer ? Wf2 : Wf1;
    const float* Ws = layer ? Ws2 : Ws1;
    const int i = blockIdx.x * 256 + threadIdx.x;   // 0..1279
    if (i < 1024) {
        const int p    = i >> 9;
        const int cbi  = (i >> 6) & 7;
        const int l    = i & 63;
        const int n16  = l & 15, quad = l >> 4, kc = quad * 8;
        const int col  = cbi * 16 + n16;
        const int j    = col >> 1;
        const float* Wsel = (col & 1) ? Ws : Wf;
        const int rbase = p * 64;
        U4 b0, b1;
#pragma unroll
        for (int pp = 0; pp < 4; ++pp) {
            b0.u[pp] = pk_bf16(Wsel[(rbase + kc + 2 * pp) * 64 + j],
                               Wsel[(rbase + kc + 2 * pp + 1) * 64 + j]);
            b1.u[pp] = pk_bf16(Wsel[(rbase + 32 + kc + 2 * pp) * 64 + j],
                               Wsel[(rbase + 32 + kc + 2 * pp + 1) * 64 + j]);
        }
        uint4* o = WpkNT + ((size_t)layer * 1024 + i) * 2;
        o[0] = b0.v; o[1] = b1.v;
    } else if (i < 1280) {
        const int k  = i - 1024;
        const int jb = k >> 6;
        const int l  = k & 63;
        const int n16 = l & 15, quad = l >> 4, c0 = quad * 8;
        const int j = n16 * 4 + jb;
        U4 bf_, bs_;
#pragma unroll
        for (int pp = 0; pp < 4; ++pp) {
            bf_.u[pp] = pk_bf16(Wf[(128 + c0 + 2 * pp) * 64 + j],
                                Wf[(128 + c0 + 2 * pp + 1) * 64 + j]);
            bs_.u[pp] = pk_bf16(Ws[(128 + c0 + 2 * pp) * 64 + j],
                                Ws[(128 + c0 + 2 * pp + 1) * 64 + j]);
        }
        uint4* o = WpkE + ((size_t)layer * 256 + k) * 2;
        o[0] = bf_.v; o[1] = bs_.v;
    }
}

// ---- node transform: Tdst/Tsrc = bf16[H @ W parts], (f,s)-pair layout -----
__global__ __launch_bounds__(256) void node_transform_mfma(
    const float* __restrict__ H,
    const float* __restrict__ bf,
    const float* __restrict__ bs,
    const uint4* __restrict__ Wpk,        // this layer's NT fragments
    unsigned short* __restrict__ Tdst,    // [N_NODES][128]
    unsigned short* __restrict__ Tsrc,    // [N_NODES][128]
    float* __restrict__ hinit)            // [N_NODES][64] <- copy of H
{
    __shared__ unsigned short lt[4][16 * NSTR];
    const int lane = threadIdx.x & 63;
    const int wid  = threadIdx.x >> 6;
    const int n16  = lane & 15;
    const int quad = lane >> 4;
    const int kc   = quad * 8;
    unsigned short* L = lt[wid];

    const int gid = blockIdx.x * 4 + wid;           // global wave id
    const int NW  = (N_NODES / 16) * 2;             // 6250 waves of work
    if (gid >= NW) return;
    const int ntile = gid >> 1;
    const int part  = gid & 1;                      // 0: dst-part, 1: src-part
    unsigned short* Tout = part ? Tsrc : Tdst;

    // A fragments once per wave
    const float* hrow = H + (size_t)(ntile * 16 + n16) * D;
    float4 q0 = *(const float4*)(hrow + kc);
    float4 q1 = *(const float4*)(hrow + kc + 4);
    float4 q2 = *(const float4*)(hrow + 32 + kc);
    float4 q3 = *(const float4*)(hrow + 32 + kc + 4);
    Frag a0, a1;
    a0.u[0] = pk_bf16(q0.x, q0.y); a0.u[1] = pk_bf16(q0.z, q0.w);
    a0.u[2] = pk_bf16(q1.x, q1.y); a0.u[3] = pk_bf16(q1.z, q1.w);
    a1.u[0] = pk_bf16(q2.x, q2.y); a1.u[1] = pk_bf16(q2.z, q2.w);
    a1.u[2] = pk_bf16(q3.x, q3.y); a1.u[3] = pk_bf16(q3.z, q3.w);

    // fused h-init copy (h = H), one writer per node tile
    if (part == 0) {
        float4* hp = (float4*)(hinit + (size_t)(ntile * 16 + n16) * D);
        hp[quad * 2]     = q0;
        hp[quad * 2 + 1] = q1;
        hp[8 + quad * 2] = q2;
        hp[9 + quad * 2] = q3;
    }

#pragma unroll
    for (int cbi = 0; cbi < 8; ++cbi) {
        const int col   = cbi * 16 + n16;    // 0..127 within this part
        const int sflag = col & 1;           // 0: f, 1: s
        const int j     = col >> 1;          // output channel 0..63

        Frag b0, b1;
        {
            const uint4* bp = Wpk + ((size_t)(part * 512 + cbi * 64 + lane)) * 2;
            *(uint4*)&b0 = bp[0];
            *(uint4*)&b1 = bp[1];
        }
        float bias = 0.0f;
        if (part == 0) bias = sflag ? bs[j] : bf[j];

        floatx4 acc = {bias, bias, bias, bias};
        acc = __builtin_amdgcn_mfma_f32_16x16x32_bf16(a0.s, b0.s, acc, 0, 0, 0);
        acc = __builtin_amdgcn_mfma_f32_16x16x32_bf16(a1.s, b1.s, acc, 0, 0, 0);

#pragma unroll
        for (int r = 0; r < 4; ++r)
            L[(quad * 4 + r) * NSTR + col] = bf16_1(acc[r]);
    }

    // wave-private tile -> coalesced stores (no barrier needed; same wave)
#pragma unroll
    for (int it = 0; it < 4; ++it) {
        const int node_l = it * 4 + quad;            // local node 0..15
        const int c8     = n16 * 8;                  // col group (8 ushorts)
        uint4 v = *(const uint4*)(L + node_l * NSTR + c8);
        *(uint4*)(Tout + (size_t)(ntile * 16 + node_l) * 128 + c8) = v;
    }
}

// ---- edge kernel: per-quad register run-length aggregation (R13) ----------
// Permuted A-row map: row m of MFMA tt <- edge base + 16*(m>>2) + (m&3) + 4*tt
// => quad q's C/D rows traverse edges base+16q .. base+16q+15 in order.
__global__ __launch_bounds__(256) void edge_message_mfma(
    const unsigned short* __restrict__ Tdst,  // [N_NODES][128] bf16
    const unsigned short* __restrict__ Tsrc,  // [N_NODES][128] bf16
    const unsigned short* __restrict__ eaS,   // [N_EDGES][32] bf16, sorted
    const int2* __restrict__ sd_sorted,       // [N_EDGES] (src,dst) sorted
    const uint4* __restrict__ WpkE,           // this layer's edge fragments
    float* __restrict__ hout)                 // [N_NODES][64], pre-init = hin
{
    const int lane = threadIdx.x & 63;
    const int wid  = threadIdx.x >> 6;
    const int n16  = lane & 15;
    const int quad = lane >> 4;
    const int c0   = quad * 8;

    Frag bfr[4], bsr[4];
#pragma unroll
    for (int jb = 0; jb < 4; ++jb) {
        *(uint4*)&bfr[jb] = WpkE[((size_t)(jb * 64 + lane)) * 2 + 0];
        *(uint4*)&bsr[jb] = WpkE[((size_t)(jb * 64 + lane)) * 2 + 1];
    }

    // bijective XCD swizzle (nwg = 3125, q = 390, rr = 5)
    const int nwg = gridDim.x;
    const int xcd = blockIdx.x & 7;
    const int idx = blockIdx.x >> 3;
    const int q   = nwg >> 3, rr = nwg & 7;
    const int sb  = (xcd < rr ? xcd * (q + 1) : rr * (q + 1) + (xcd - rr) * q) + idx;
    const int w   = sb * 4 + wid;            // wave slot 0..12499
    const int base = w * 64;                 // first of 64 consecutive edges

    const floatx4 zero = {0.0f, 0.0f, 0.0f, 0.0f};

    // per-lane A pointer: edge(base, n16, tt=0), k-chunk c0
    const unsigned short* aptr =
        eaS + (size_t)(base + (n16 >> 2) * 16 + (n16 & 3)) * 32 + c0;
    // per-quad sd pointer: quad q's edges start at base + 16q
    const int2* sdp = sd_sorted + base + quad * 16;

    // per-quad run-length state
    int   cur_d = -1;
    U4    dreg; dreg.v = make_uint4(0u, 0u, 0u, 0u);
    float acc0 = 0.f, acc1 = 0.f, acc2 = 0.f, acc3 = 0.f;

    Frag af;
    af.s = *(const short8*)aptr;

#pragma unroll 1
    for (int tt = 0; tt < 4; ++tt) {
        floatx4 accf[4], accs[4];
#pragma unroll
        for (int jb = 0; jb < 4; ++jb) {
            accf[jb] = __builtin_amdgcn_mfma_f32_16x16x32_bf16(af.s, bfr[jb].s, zero, 0, 0, 0);
            accs[jb] = __builtin_amdgcn_mfma_f32_16x16x32_bf16(af.s, bsr[jb].s, zero, 0, 0, 0);
        }
        // prefetch next A fragment (edges advance by 4 -> 128 ushorts)
        if (tt < 3) af.s = *(const short8*)(aptr + (tt + 1) * 128);

        const int2* sdt = sdp + 4 * tt;           // quad-uniform rows

#pragma unroll
        for (int r = 0; r < 4; ++r) {
            const int2 sdm = sdt[r];              // 16-lane broadcast load
            U4 s4;
            s4.v = *(const uint4*)(Tsrc + (size_t)sdm.x * 128 + n16 * 8);
            const int dv = sdm.y;
            if (dv != cur_d) {
                if (cur_d >= 0) {
                    float* hp = hout + (size_t)cur_d * D + n16 * 4;
                    atomicAdd(hp + 0, acc0);
                    atomicAdd(hp + 1, acc1);
                    atomicAdd(hp + 2, acc2);
                    atomicAdd(hp + 3, acc3);
                }
                cur_d = dv;
                dreg.v = *(const uint4*)(Tdst + (size_t)dv * 128 + n16 * 8);
                acc0 = acc1 = acc2 = acc3 = 0.f;
            }
#pragma unroll
            for (int jb = 0; jb < 4; ++jb) {
                unsigned d2 = dreg.u[jb];
                unsigned s2 = s4.u[jb];
                float vf = accf[jb][r] + upk(d2 & 0xFFFFu) + upk(s2 & 0xFFFFu);
                float vs = accs[jb][r] + upk(d2 >> 16) + upk(s2 >> 16);
                float sig = __builtin_amdgcn_rcpf(1.0f + __expf(-vf));
                float spl = fmaxf(vs, 0.0f) + __logf(1.0f + __expf(-fabsf(vs)));
                float msg = sig * spl;
                if      (jb == 0) acc0 += msg;
                else if (jb == 1) acc1 += msg;
                else if (jb == 2) acc2 += msg;
                else              acc3 += msg;
            }
        }
    }
    // final flush (cur_d always valid here)
    {
        float* hp = hout + (size_t)cur_d * D + n16 * 4;
        atomicAdd(hp + 0, acc0);
        atomicAdd(hp + 1, acc1);
        atomicAdd(hp + 2, acc2);
        atomicAdd(hp + 3, acc3);
    }
}

// segment_sum(h, batch) into pooled[N_GRAPHS][64]
// sorted batch -> run-length accumulate 16 nodes per wave
__global__ __launch_bounds__(256) void pool_kernel(
    const float* __restrict__ h,
    const int* __restrict__ batch,
    float* __restrict__ pooled)
{
    const int lane = threadIdx.x & 63;
    const int wid  = threadIdx.x >> 6;
    const int w = blockIdx.x * 4 + wid;
    const int n0 = w * 16;
    if (n0 >= N_NODES) return;
    const int nend = (n0 + 16 < N_NODES) ? (n0 + 16) : N_NODES;

    int cur = batch[n0];
    float acc = 0.0f;
    for (int n = n0; n < nend; ++n) {
        int b = batch[n];                      // wave-uniform scalar load
        float v = h[(size_t)n * D + lane];
        if (b != cur) {
            atomicAdd(&pooled[(size_t)cur * D + lane], acc);
            cur = b; acc = v;
        } else {
            acc += v;
        }
    }
    atomicAdd(&pooled[(size_t)cur * D + lane], acc);
}

__global__ __launch_bounds__(256) void out_kernel(
    const float* __restrict__ pooled,
    const float* __restrict__ Wout,
    const float* __restrict__ bout,
    float* __restrict__ out)
{
    const int g = blockIdx.x * blockDim.x + threadIdx.x;
    if (g >= N_GRAPHS) return;
    float acc = bout[0];
#pragma unroll
    for (int j = 0; j < D; ++j) acc = fmaf(pooled[(size_t)g * D + j], Wout[j], acc);
    out[g] = acc;
}

extern "C" void kernel_launch(void* const* d_in, const int* in_sizes, int n_in,
                              void* d_out, int out_size, void* d_ws, size_t ws_size,
                              hipStream_t stream) {
    const float* x     = (const float*)d_in[0];
    const int*   ei    = (const int*)  d_in[1];
    const float* ea    = (const float*)d_in[2];
    const int*   batch = (const int*)  d_in[3];
    const float* Wf1   = (const float*)d_in[4];
    const float* bf1   = (const float*)d_in[5];
    const float* Ws1   = (const float*)d_in[6];
    const float* bs1   = (const float*)d_in[7];
    const float* Wf2   = (const float*)d_in[8];
    const float* bf2   = (const float*)d_in[9];
    const float* Ws2   = (const float*)d_in[10];
    const float* bs2   = (const float*)d_in[11];
    const float* Wout  = (const float*)d_in[12];
    const float* bout  = (const float*)d_in[13];
    float* out = (float*)d_out;

    // workspace carve (~110 MB)
    char* base = (char*)d_ws;
    size_t o = 0;
    unsigned short* Tdst = (unsigned short*)(base + o); o += (size_t)N_NODES * 128 * 2;
    unsigned short* Tsrc = (unsigned short*)(base + o); o += (size_t)N_NODES * 128 * 2;
    unsigned short* eaS  = (unsigned short*)(base + o); o += (size_t)N_EDGES * 32 * 2;
    float* h1     = (float*)(base + o); o += (size_t)N_NODES * D * 4;
    float* h2     = (float*)(base + o); o += (size_t)N_NODES * D * 4;
    float* pooled = (float*)(base + o); o += (size_t)N_GRAPHS * D * 4;
    int* deg  = (int*)(base + o); o += (size_t)N_NODES * 4;
    int* off  = (int*)(base + o); o += (size_t)(N_NODES + 1) * 4;
    int* tsum = (int*)(base + o); o += 256 * 4;
    int2* sd_sorted = (int2*)(base + o); o += (size_t)N_EDGES * 8;
    uint4* WpkNT = (uint4*)(base + o); o += (size_t)2 * 1024 * 2 * 16;
    uint4* WpkE  = (uint4*)(base + o); o += (size_t)2 * 256 * 2 * 16;

    // ---- W fragment pack (both layers, both layouts) ----
    pack_W<<<dim3(5, 2), 256, 0, stream>>>(Wf1, Ws1, Wf2, Ws2, WpkNT, WpkE);

    // ---- CSR build + fused ea pack ----
    hipMemsetAsync(deg, 0, (size_t)N_NODES * 4, stream);
    hist_kernel<<<N_EDGES / 256, 256, 0, stream>>>(ei, deg);
    scan1<<<NB_SCAN, 256, 0, stream>>>(deg, off, tsum);
    scan2<<<1, 256, 0, stream>>>(tsum);
    scan3<<<NB_SCAN, 256, 0, stream>>>(off, tsum);
    hipMemsetAsync(deg, 0, (size_t)N_NODES * 4, stream);
    scatter_pack<<<N_EDGES / 256, 256, 0, stream>>>(ei, off, deg, ea, eaS, sd_sorted);

    // ---- layer 1 ----  (node_transform also writes h1 = x)
    node_transform_mfma<<<1563, 256, 0, stream>>>(x, bf1, bs1, WpkNT, Tdst, Tsrc, h1);
    edge_message_mfma<<<3125, 256, 0, stream>>>(Tdst, Tsrc, eaS, sd_sorted,
                                                WpkE, h1);

    // ---- layer 2 ----  (node_transform also writes h2 = h1)
    node_transform_mfma<<<1563, 256, 0, stream>>>(h1, bf2, bs2, WpkNT + 2048, Tdst, Tsrc, h2);
    edge_message_mfma<<<3125, 256, 0, stream>>>(Tdst, Tsrc, eaS, sd_sorted,
                                                WpkE + 512, h2);

    // ---- pool + out ----
    hipMemsetAsync(pooled, 0, (size_t)N_GRAPHS * D * 4, stream);
    pool_kernel<<<782, 256, 0, stream>>>(h2, batch, pooled);
    out_kernel<<<2, 256, 0, stream>>>(pooled, Wout, bout, out);
}

// Round 5
// 446.492 us; speedup vs baseline: 1.6500x; 1.1492x over previous
//
#include <hip/hip_runtime.h>
#include <math.h>

#define N_NODES 50000
#define N_EDGES 800000
#define N_GRAPHS 512
#define D 64
#define DE 32
#define NTILE (N_EDGES / 16)   // 50000 16-edge tiles
#define NB_SCAN 196            // ceil(50000/256)
#define NSTR 136               // NT LDS row stride (ushorts), 272B = 16B-aligned

// ---------------------------------------------------------------------------
// R14: empirical atomic law (fit across R11/R12/R13 counters): HBM write
// bytes ~= sum over atomic INSTRUCTIONS of 64B-lines touched. R13's flush
// (4 inst x 16 lanes stride-16B = 4 lines/inst) cost 4x R11's (1 inst x 64
// lanes contiguous). Fix: edge C/D column map back to j = 16*jb + n16 so
// each flush instruction writes 16 lanes x contiguous 64B = 1 line.
// Gathers become 4 dword loads per T row (same lines, 3 extra VMEM issues)
// — cheap vs the write-path penalty. Keep R13's no-LDS/no-scan run-length
// structure with consecutive-16-edge quad ownership:
//   A row m of MFMA tt  <-  edge base + 16*(m>>2) + (m&3) + 4*tt
//   => quad q processes edges base+16q .. base+16q+15 IN ORDER.
//
// MFMA 16x16x32 bf16 fragment maps (m89/m120-verified):
//   A[m][k]: m = lane&15, k = (lane>>4)*8 + i
//   B[k][n]: n = lane&15, k = (lane>>4)*8 + i
//   C/D    : col n = lane&15, row m = (lane>>4)*4 + reg
// Edge column map (R14): column n16 of call jb holds channel j = 16*jb+n16;
// T-row dword j = (f_j | s_j<<16) pair, so lane reads dwords {16jb+n16}.
// ---------------------------------------------------------------------------

typedef __attribute__((ext_vector_type(8))) short short8;
typedef __attribute__((ext_vector_type(4))) float floatx4;
union Frag { short8 s; unsigned u[4]; };
union U4   { uint4 v; unsigned u[4]; };

__device__ inline unsigned pk_bf16(float lo, float hi) {
    unsigned a = __float_as_uint(lo);
    unsigned b = __float_as_uint(hi);
    a = (a + 0x7FFFu + ((a >> 16) & 1u)) >> 16;
    b = (b + 0x7FFFu + ((b >> 16) & 1u)) >> 16;
    return a | (b << 16);
}
__device__ inline unsigned short bf16_1(float v) {
    unsigned a = __float_as_uint(v);
    return (unsigned short)((a + 0x7FFFu + ((a >> 16) & 1u)) >> 16);
}
__device__ inline float upk(unsigned u16) { return __uint_as_float(u16 << 16); }

// ---------------- CSR build (once per call) --------------------------------
__global__ __launch_bounds__(256) void hist_kernel(
    const int* __restrict__ ei, int* __restrict__ deg)
{
    int e = blockIdx.x * 256 + threadIdx.x;
    atomicAdd(&deg[ei[N_EDGES + e]], 1);
}

__global__ __launch_bounds__(256) void scan1(
    const int* __restrict__ deg, int* __restrict__ off, int* __restrict__ tsum)
{
    __shared__ int s[256];
    int i = blockIdx.x * 256 + threadIdx.x;
    s[threadIdx.x] = (i < N_NODES) ? deg[i] : 0;
    __syncthreads();
    if (threadIdx.x == 0) {
        int run = 0;
        for (int k = 0; k < 256; ++k) { int t = s[k]; s[k] = run; run += t; }
        tsum[blockIdx.x] = run;
    }
    __syncthreads();
    if (i < N_NODES) off[i] = s[threadIdx.x];
}

__global__ __launch_bounds__(256) void scan2(int* __restrict__ tsum)
{
    __shared__ int s[256];
    int i = threadIdx.x;
    s[i] = (i < NB_SCAN) ? tsum[i] : 0;
    __syncthreads();
    if (i == 0) {
        int run = 0;
        for (int k = 0; k < NB_SCAN; ++k) { int t = s[k]; s[k] = run; run += t; }
    }
    __syncthreads();
    if (i < NB_SCAN) tsum[i] = s[i];
}

__global__ __launch_bounds__(256) void scan3(
    int* __restrict__ off, const int* __restrict__ tsum)
{
    int i = blockIdx.x * 256 + threadIdx.x;
    if (i < N_NODES) off[i] += tsum[blockIdx.x];
    if (i == N_NODES) off[i] = N_EDGES;
}

// scatter + ea pack in one pass: read side coalesced, write side random 64B
__global__ __launch_bounds__(256) void scatter_pack(
    const int* __restrict__ ei, const int* __restrict__ off,
    int* __restrict__ cnt, const float* __restrict__ ea,
    unsigned short* __restrict__ eaS,      // [N_EDGES][32] bf16, sorted order
    int2* __restrict__ sd_sorted)          // [N_EDGES] (src,dst), sorted
{
    int e = blockIdx.x * 256 + threadIdx.x;
    int s = ei[e];
    int d = ei[N_EDGES + e];
    int r = atomicAdd(&cnt[d], 1);
    int pos = off[d] + r;
    sd_sorted[pos] = make_int2(s, d);

    const float4* src4 = (const float4*)(ea + (size_t)e * 32);
    uint4* dst16 = (uint4*)(eaS + (size_t)pos * 32);
#pragma unroll
    for (int q = 0; q < 2; ++q) {
        float4 v0 = src4[4 * q + 0];
        float4 v1 = src4[4 * q + 1];
        float4 v2 = src4[4 * q + 2];
        float4 v3 = src4[4 * q + 3];
        uint4 o0;
        o0.x = pk_bf16(v0.x, v0.y); o0.y = pk_bf16(v0.z, v0.w);
        o0.z = pk_bf16(v1.x, v1.y); o0.w = pk_bf16(v1.z, v1.w);
        uint4 o1;
        o1.x = pk_bf16(v2.x, v2.y); o1.y = pk_bf16(v2.z, v2.w);
        o1.z = pk_bf16(v3.x, v3.y); o1.w = pk_bf16(v3.z, v3.w);
        dst16[2 * q + 0] = o0;
        dst16[2 * q + 1] = o1;
    }
}

// ---- B-fragment precompute --------------------------------------------------
// WpkNT: [layer][part(2)][cbi(8)][lane(64)][2] uint4  (NT layout, j = col>>1)
// WpkE : [layer][jb(4)][lane(64)][2] uint4           (edge layout, j = 16jb+n16)
__global__ __launch_bounds__(256) void pack_W(
    const float* __restrict__ Wf1, const float* __restrict__ Ws1,
    const float* __restrict__ Wf2, const float* __restrict__ Ws2,
    uint4* __restrict__ WpkNT, uint4* __restrict__ WpkE)
{
    const int layer = blockIdx.y;
    const float* Wf = layer ? Wf2 : Wf1;
    const float* Ws = layer ? Ws2 : Ws1;
    const int i = blockIdx.x * 256 + threadIdx.x;   // 0..1279
    if (i < 1024) {
        const int p    = i >> 9;
        const int cbi  = (i >> 6) & 7;
        const int l    = i & 63;
        const int n16  = l & 15, quad = l >> 4, kc = quad * 8;
        const int col  = cbi * 16 + n16;
        const int j    = col >> 1;
        const float* Wsel = (col & 1) ? Ws : Wf;
        const int rbase = p * 64;
        U4 b0, b1;
#pragma unroll
        for (int pp = 0; pp < 4; ++pp) {
            b0.u[pp] = pk_bf16(Wsel[(rbase + kc + 2 * pp) * 64 + j],
                               Wsel[(rbase + kc + 2 * pp + 1) * 64 + j]);
            b1.u[pp] = pk_bf16(Wsel[(rbase + 32 + kc + 2 * pp) * 64 + j],
                               Wsel[(rbase + 32 + kc + 2 * pp + 1) * 64 + j]);
        }
        uint4* o = WpkNT + ((size_t)layer * 1024 + i) * 2;
        o[0] = b0.v; o[1] = b1.v;
    } else if (i < 1280) {
        const int k  = i - 1024;
        const int jb = k >> 6;
        const int l  = k & 63;
        const int n16 = l & 15, quad = l >> 4, c0 = quad * 8;
        const int j = jb * 16 + n16;             // R14: contiguous-flush map
        U4 bf_, bs_;
#pragma unroll
        for (int pp = 0; pp < 4; ++pp) {
            bf_.u[pp] = pk_bf16(Wf[(128 + c0 + 2 * pp) * 64 + j],
                                Wf[(128 + c0 + 2 * pp + 1) * 64 + j]);
            bs_.u[pp] = pk_bf16(Ws[(128 + c0 + 2 * pp) * 64 + j],
                                Ws[(128 + c0 + 2 * pp + 1) * 64 + j]);
        }
        uint4* o = WpkE + ((size_t)layer * 256 + k) * 2;
        o[0] = bf_.v; o[1] = bs_.v;
    }
}

// ---- node transform: Tdst/Tsrc = bf16[H @ W parts], (f,s)-pair layout -----
__global__ __launch_bounds__(256) void node_transform_mfma(
    const float* __restrict__ H,
    const float* __restrict__ bf,
    const float* __restrict__ bs,
    const uint4* __restrict__ Wpk,        // this layer's NT fragments
    unsigned short* __restrict__ Tdst,    // [N_NODES][128]
    unsigned short* __restrict__ Tsrc,    // [N_NODES][128]
    float* __restrict__ hinit)            // [N_NODES][64] <- copy of H
{
    __shared__ unsigned short lt[4][16 * NSTR];
    const int lane = threadIdx.x & 63;
    const int wid  = threadIdx.x >> 6;
    const int n16  = lane & 15;
    const int quad = lane >> 4;
    const int kc   = quad * 8;
    unsigned short* L = lt[wid];

    const int gid = blockIdx.x * 4 + wid;           // global wave id
    const int NW  = (N_NODES / 16) * 2;             // 6250 waves of work
    if (gid >= NW) return;
    const int ntile = gid >> 1;
    const int part  = gid & 1;                      // 0: dst-part, 1: src-part
    unsigned short* Tout = part ? Tsrc : Tdst;

    // A fragments once per wave
    const float* hrow = H + (size_t)(ntile * 16 + n16) * D;
    float4 q0 = *(const float4*)(hrow + kc);
    float4 q1 = *(const float4*)(hrow + kc + 4);
    float4 q2 = *(const float4*)(hrow + 32 + kc);
    float4 q3 = *(const float4*)(hrow + 32 + kc + 4);
    Frag a0, a1;
    a0.u[0] = pk_bf16(q0.x, q0.y); a0.u[1] = pk_bf16(q0.z, q0.w);
    a0.u[2] = pk_bf16(q1.x, q1.y); a0.u[3] = pk_bf16(q1.z, q1.w);
    a1.u[0] = pk_bf16(q2.x, q2.y); a1.u[1] = pk_bf16(q2.z, q2.w);
    a1.u[2] = pk_bf16(q3.x, q3.y); a1.u[3] = pk_bf16(q3.z, q3.w);

    // fused h-init copy (h = H), one writer per node tile
    if (part == 0) {
        float4* hp = (float4*)(hinit + (size_t)(ntile * 16 + n16) * D);
        hp[quad * 2]     = q0;
        hp[quad * 2 + 1] = q1;
        hp[8 + quad * 2] = q2;
        hp[9 + quad * 2] = q3;
    }

#pragma unroll
    for (int cbi = 0; cbi < 8; ++cbi) {
        const int col   = cbi * 16 + n16;    // 0..127 within this part
        const int sflag = col & 1;           // 0: f, 1: s
        const int j     = col >> 1;          // output channel 0..63

        Frag b0, b1;
        {
            const uint4* bp = Wpk + ((size_t)(part * 512 + cbi * 64 + lane)) * 2;
            *(uint4*)&b0 = bp[0];
            *(uint4*)&b1 = bp[1];
        }
        float bias = 0.0f;
        if (part == 0) bias = sflag ? bs[j] : bf[j];

        floatx4 acc = {bias, bias, bias, bias};
        acc = __builtin_amdgcn_mfma_f32_16x16x32_bf16(a0.s, b0.s, acc, 0, 0, 0);
        acc = __builtin_amdgcn_mfma_f32_16x16x32_bf16(a1.s, b1.s, acc, 0, 0, 0);

#pragma unroll
        for (int r = 0; r < 4; ++r)
            L[(quad * 4 + r) * NSTR + col] = bf16_1(acc[r]);
    }

    // wave-private tile -> coalesced stores (no barrier needed; same wave)
#pragma unroll
    for (int it = 0; it < 4; ++it) {
        const int node_l = it * 4 + quad;            // local node 0..15
        const int c8     = n16 * 8;                  // col group (8 ushorts)
        uint4 v = *(const uint4*)(L + node_l * NSTR + c8);
        *(uint4*)(Tout + (size_t)(ntile * 16 + node_l) * 128 + c8) = v;
    }
}

// ---- edge kernel: per-quad register run-length aggregation (R14) ----------
// Permuted A-row map: row m of MFMA tt <- edge base + 16*(m>>2) + (m&3) + 4*tt
// => quad q's C/D rows traverse edges base+16q .. base+16q+15 in order.
// Column map j = 16jb+n16: flush inst jb = 16 lanes contiguous 64B (1 line).
__global__ __launch_bounds__(256) void edge_message_mfma(
    const unsigned short* __restrict__ Tdst,  // [N_NODES][128] bf16
    const unsigned short* __restrict__ Tsrc,  // [N_NODES][128] bf16
    const unsigned short* __restrict__ eaS,   // [N_EDGES][32] bf16, sorted
    const int2* __restrict__ sd_sorted,       // [N_EDGES] (src,dst) sorted
    const uint4* __restrict__ WpkE,           // this layer's edge fragments
    float* __restrict__ hout)                 // [N_NODES][64], pre-init = hin
{
    const int lane = threadIdx.x & 63;
    const int wid  = threadIdx.x >> 6;
    const int n16  = lane & 15;
    const int quad = lane >> 4;
    const int c0   = quad * 8;

    Frag bfr[4], bsr[4];
#pragma unroll
    for (int jb = 0; jb < 4; ++jb) {
        *(uint4*)&bfr[jb] = WpkE[((size_t)(jb * 64 + lane)) * 2 + 0];
        *(uint4*)&bsr[jb] = WpkE[((size_t)(jb * 64 + lane)) * 2 + 1];
    }

    // bijective XCD swizzle (nwg = 3125, q = 390, rr = 5)
    const int nwg = gridDim.x;
    const int xcd = blockIdx.x & 7;
    const int idx = blockIdx.x >> 3;
    const int q   = nwg >> 3, rr = nwg & 7;
    const int sb  = (xcd < rr ? xcd * (q + 1) : rr * (q + 1) + (xcd - rr) * q) + idx;
    const int w   = sb * 4 + wid;            // wave slot 0..12499
    const int base = w * 64;                 // first of 64 consecutive edges

    const floatx4 zero = {0.0f, 0.0f, 0.0f, 0.0f};

    // per-lane A pointer: edge(base, n16, tt=0), k-chunk c0
    const unsigned short* aptr =
        eaS + (size_t)(base + (n16 >> 2) * 16 + (n16 & 3)) * 32 + c0;
    // per-quad sd pointer: quad q's edges start at base + 16q
    const int2* sdp = sd_sorted + base + quad * 16;

    // per-quad run-length state (channel jb*16+n16 in acc_jb)
    int cur_d = -1;
    unsigned dr0 = 0, dr1 = 0, dr2 = 0, dr3 = 0;
    float acc0 = 0.f, acc1 = 0.f, acc2 = 0.f, acc3 = 0.f;

    Frag af;
    af.s = *(const short8*)aptr;

#pragma unroll 1
    for (int tt = 0; tt < 4; ++tt) {
        floatx4 accf[4], accs[4];
#pragma unroll
        for (int jb = 0; jb < 4; ++jb) {
            accf[jb] = __builtin_amdgcn_mfma_f32_16x16x32_bf16(af.s, bfr[jb].s, zero, 0, 0, 0);
            accs[jb] = __builtin_amdgcn_mfma_f32_16x16x32_bf16(af.s, bsr[jb].s, zero, 0, 0, 0);
        }
        // prefetch next A fragment (edges advance by 4 -> 128 ushorts)
        if (tt < 3) af.s = *(const short8*)(aptr + (tt + 1) * 128);

        const int2* sdt = sdp + 4 * tt;           // quad-uniform rows

#pragma unroll
        for (int r = 0; r < 4; ++r) {
            const int2 sdm = sdt[r];              // 16-lane broadcast load
            const unsigned* srow = (const unsigned*)(Tsrc + (size_t)sdm.x * 128);
            unsigned s0 = srow[n16];              // 4 x dword, 1 line each
            unsigned s1 = srow[16 + n16];
            unsigned s2 = srow[32 + n16];
            unsigned s3 = srow[48 + n16];
            const int dv = sdm.y;
            if (dv != cur_d) {
                if (cur_d >= 0) {
                    float* hp = hout + (size_t)cur_d * D + n16;
                    atomicAdd(hp +  0, acc0);     // 16 lanes x 64B contiguous
                    atomicAdd(hp + 16, acc1);
                    atomicAdd(hp + 32, acc2);
                    atomicAdd(hp + 48, acc3);
                }
                cur_d = dv;
                const unsigned* drow = (const unsigned*)(Tdst + (size_t)dv * 128);
                dr0 = drow[n16];
                dr1 = drow[16 + n16];
                dr2 = drow[32 + n16];
                dr3 = drow[48 + n16];
                acc0 = acc1 = acc2 = acc3 = 0.f;
            }
#pragma unroll
            for (int jb = 0; jb < 4; ++jb) {
                unsigned d2 = (jb == 0) ? dr0 : (jb == 1) ? dr1 : (jb == 2) ? dr2 : dr3;
                unsigned sv = (jb == 0) ? s0  : (jb == 1) ? s1  : (jb == 2) ? s2  : s3;
                float vf = accf[jb][r] + upk(d2 & 0xFFFFu) + upk(sv & 0xFFFFu);
                float vs = accs[jb][r] + upk(d2 >> 16) + upk(sv >> 16);
                float sig = __builtin_amdgcn_rcpf(1.0f + __expf(-vf));
                float spl = fmaxf(vs, 0.0f) + __logf(1.0f + __expf(-fabsf(vs)));
                float msg = sig * spl;
                if      (jb == 0) acc0 += msg;
                else if (jb == 1) acc1 += msg;
                else if (jb == 2) acc2 += msg;
                else              acc3 += msg;
            }
        }
    }
    // final flush (cur_d always valid here)
    {
        float* hp = hout + (size_t)cur_d * D + n16;
        atomicAdd(hp +  0, acc0);
        atomicAdd(hp + 16, acc1);
        atomicAdd(hp + 32, acc2);
        atomicAdd(hp + 48, acc3);
    }
}

// segment_sum(h, batch) into pooled[N_GRAPHS][64]
// sorted batch -> run-length accumulate 16 nodes per wave
__global__ __launch_bounds__(256) void pool_kernel(
    const float* __restrict__ h,
    const int* __restrict__ batch,
    float* __restrict__ pooled)
{
    const int lane = threadIdx.x & 63;
    const int wid  = threadIdx.x >> 6;
    const int w = blockIdx.x * 4 + wid;
    const int n0 = w * 16;
    if (n0 >= N_NODES) return;
    const int nend = (n0 + 16 < N_NODES) ? (n0 + 16) : N_NODES;

    int cur = batch[n0];
    float acc = 0.0f;
    for (int n = n0; n < nend; ++n) {
        int b = batch[n];                      // wave-uniform scalar load
        float v = h[(size_t)n * D + lane];
        if (b != cur) {
            atomicAdd(&pooled[(size_t)cur * D + lane], acc);
            cur = b; acc = v;
        } else {
            acc += v;
        }
    }
    atomicAdd(&pooled[(size_t)cur * D + lane], acc);
}

__global__ __launch_bounds__(256) void out_kernel(
    const float* __restrict__ pooled,
    const float* __restrict__ Wout,
    const float* __restrict__ bout,
    float* __restrict__ out)
{
    const int g = blockIdx.x * blockDim.x + threadIdx.x;
    if (g >= N_GRAPHS) return;
    float acc = bout[0];
#pragma unroll
    for (int j = 0; j < D; ++j) acc = fmaf(pooled[(size_t)g * D + j], Wout[j], acc);
    out[g] = acc;
}

extern "C" void kernel_launch(void* const* d_in, const int* in_sizes, int n_in,
                              void* d_out, int out_size, void* d_ws, size_t ws_size,
                              hipStream_t stream) {
    const float* x     = (const float*)d_in[0];
    const int*   ei    = (const int*)  d_in[1];
    const float* ea    = (const float*)d_in[2];
    const int*   batch = (const int*)  d_in[3];
    const float* Wf1   = (const float*)d_in[4];
    const float* bf1   = (const float*)d_in[5];
    const float* Ws1   = (const float*)d_in[6];
    const float* bs1   = (const float*)d_in[7];
    const float* Wf2   = (const float*)d_in[8];
    const float* bf2   = (const float*)d_in[9];
    const float* Ws2   = (const float*)d_in[10];
    const float* bs2   = (const float*)d_in[11];
    const float* Wout  = (const float*)d_in[12];
    const float* bout  = (const float*)d_in[13];
    float* out = (float*)d_out;

    // workspace carve (~110 MB)
    char* base = (char*)d_ws;
    size_t o = 0;
    unsigned short* Tdst = (unsigned short*)(base + o); o += (size_t)N_NODES * 128 * 2;
    unsigned short* Tsrc = (unsigned short*)(base + o); o += (size_t)N_NODES * 128 * 2;
    unsigned short* eaS  = (unsigned short*)(base + o); o += (size_t)N_EDGES * 32 * 2;
    float* h1     = (float*)(base + o); o += (size_t)N_NODES * D * 4;
    float* h2     = (float*)(base + o); o += (size_t)N_NODES * D * 4;
    float* pooled = (float*)(base + o); o += (size_t)N_GRAPHS * D * 4;
    int* deg  = (int*)(base + o); o += (size_t)N_NODES * 4;
    int* off  = (int*)(base + o); o += (size_t)(N_NODES + 1) * 4;
    int* tsum = (int*)(base + o); o += 256 * 4;
    int2* sd_sorted = (int2*)(base + o); o += (size_t)N_EDGES * 8;
    uint4* WpkNT = (uint4*)(base + o); o += (size_t)2 * 1024 * 2 * 16;
    uint4* WpkE  = (uint4*)(base + o); o += (size_t)2 * 256 * 2 * 16;

    // ---- W fragment pack (both layers, both layouts) ----
    pack_W<<<dim3(5, 2), 256, 0, stream>>>(Wf1, Ws1, Wf2, Ws2, WpkNT, WpkE);

    // ---- CSR build + fused ea pack ----
    hipMemsetAsync(deg, 0, (size_t)N_NODES * 4, stream);
    hist_kernel<<<N_EDGES / 256, 256, 0, stream>>>(ei, deg);
    scan1<<<NB_SCAN, 256, 0, stream>>>(deg, off, tsum);
    scan2<<<1, 256, 0, stream>>>(tsum);
    scan3<<<NB_SCAN, 256, 0, stream>>>(off, tsum);
    hipMemsetAsync(deg, 0, (size_t)N_NODES * 4, stream);
    scatter_pack<<<N_EDGES / 256, 256, 0, stream>>>(ei, off, deg, ea, eaS, sd_sorted);

    // ---- layer 1 ----  (node_transform also writes h1 = x)
    node_transform_mfma<<<1563, 256, 0, stream>>>(x, bf1, bs1, WpkNT, Tdst, Tsrc, h1);
    edge_message_mfma<<<3125, 256, 0, stream>>>(Tdst, Tsrc, eaS, sd_sorted,
                                                WpkE, h1);

    // ---- layer 2 ----  (node_transform also writes h2 = h1)
    node_transform_mfma<<<1563, 256, 0, stream>>>(h1, bf2, bs2, WpkNT + 2048, Tdst, Tsrc, h2);
    edge_message_mfma<<<3125, 256, 0, stream>>>(Tdst, Tsrc, eaS, sd_sorted,
                                                WpkE + 512, h2);

    // ---- pool + out ----
    hipMemsetAsync(pooled, 0, (size_t)N_GRAPHS * D * 4, stream);
    pool_kernel<<<782, 256, 0, stream>>>(h2, batch, pooled);
    out_kernel<<<2, 256, 0, stream>>>(pooled, Wout, bout, out);
}

// Round 6
// 440.727 us; speedup vs baseline: 1.6716x; 1.0131x over previous
//
#include <hip/hip_runtime.h>
#include <math.h>

#define N_NODES 50000
#define N_EDGES 800000
#define N_GRAPHS 512
#define D 64
#define DE 32
#define NB_SCAN 196            // ceil(50000/256)
#define NSTR 136               // NT LDS row stride (ushorts), 272B = 16B-aligned
#define NB_SCAT 3125           // scatter blocks (800K/256)
#define NB_NT 1563             // node-transform blocks (6250 waves / 4)

// ---------------------------------------------------------------------------
// R15: two levers on top of R14 (446us, edge fixed at <80us):
//  1. scatter_pack (80us, VALUBusy 2.6% = pure random-write latency) FUSED
//     with node_transform L1 (independent deps, compute-heavy): one launch,
//     block-role split. Scatter's idle issue slots absorb NT's waves.
//  2. edge kernel pipelined: all 16 sd (8x int4) + all 4 A-frags preloaded;
//     each tt-group's 16 src-row dwords hoisted BEFORE the MFMAs so gather
//     latency hides under MFMA + previous activations (was: sdm load
//     immediately feeding dependent srow load = serialized chain).
// R14 atomic law (kept): HBM write bytes ~= sum over atomic INSTRUCTIONS of
// 64B lines touched -> flush uses column map j=16*jb+n16 (contiguous 64B).
//
// MFMA 16x16x32 bf16 fragment maps (m89/m120-verified):
//   A[m][k]: m = lane&15, k = (lane>>4)*8 + i
//   B[k][n]: n = lane&15, k = (lane>>4)*8 + i
//   C/D    : col n = lane&15, row m = (lane>>4)*4 + reg
// Edge A-row permutation: row m of MFMA tt <- edge base + 16*(m>>2)+(m&3)+4tt
//   => quad q processes edges base+16q .. base+16q+15 IN ORDER.
// ---------------------------------------------------------------------------

typedef __attribute__((ext_vector_type(8))) short short8;
typedef __attribute__((ext_vector_type(4))) float floatx4;
union Frag { short8 s; unsigned u[4]; };
union U4   { uint4 v; unsigned u[4]; };

__device__ inline unsigned pk_bf16(float lo, float hi) {
    unsigned a = __float_as_uint(lo);
    unsigned b = __float_as_uint(hi);
    a = (a + 0x7FFFu + ((a >> 16) & 1u)) >> 16;
    b = (b + 0x7FFFu + ((b >> 16) & 1u)) >> 16;
    return a | (b << 16);
}
__device__ inline unsigned short bf16_1(float v) {
    unsigned a = __float_as_uint(v);
    return (unsigned short)((a + 0x7FFFu + ((a >> 16) & 1u)) >> 16);
}
__device__ inline float upk(unsigned u16) { return __uint_as_float(u16 << 16); }

// ---------------- CSR build (once per call) --------------------------------
__global__ __launch_bounds__(256) void hist_kernel(
    const int* __restrict__ ei, int* __restrict__ deg)
{
    int e = blockIdx.x * 256 + threadIdx.x;
    atomicAdd(&deg[ei[N_EDGES + e]], 1);
}

__global__ __launch_bounds__(256) void scan1(
    const int* __restrict__ deg, int* __restrict__ off, int* __restrict__ tsum)
{
    __shared__ int s[256];
    int i = blockIdx.x * 256 + threadIdx.x;
    s[threadIdx.x] = (i < N_NODES) ? deg[i] : 0;
    __syncthreads();
    if (threadIdx.x == 0) {
        int run = 0;
        for (int k = 0; k < 256; ++k) { int t = s[k]; s[k] = run; run += t; }
        tsum[blockIdx.x] = run;
    }
    __syncthreads();
    if (i < N_NODES) off[i] = s[threadIdx.x];
}

__global__ __launch_bounds__(256) void scan2(int* __restrict__ tsum)
{
    __shared__ int s[256];
    int i = threadIdx.x;
    s[i] = (i < NB_SCAN) ? tsum[i] : 0;
    __syncthreads();
    if (i == 0) {
        int run = 0;
        for (int k = 0; k < NB_SCAN; ++k) { int t = s[k]; s[k] = run; run += t; }
    }
    __syncthreads();
    if (i < NB_SCAN) tsum[i] = s[i];
}

__global__ __launch_bounds__(256) void scan3(
    int* __restrict__ off, const int* __restrict__ tsum)
{
    int i = blockIdx.x * 256 + threadIdx.x;
    if (i < N_NODES) off[i] += tsum[blockIdx.x];
    if (i == N_NODES) off[i] = N_EDGES;
}

// ---- B-fragment precompute --------------------------------------------------
// WpkNT: [layer][part(2)][cbi(8)][lane(64)][2] uint4  (NT layout, j = col>>1)
// WpkE : [layer][jb(4)][lane(64)][2] uint4           (edge layout, j = 16jb+n16)
__global__ __launch_bounds__(256) void pack_W(
    const float* __restrict__ Wf1, const float* __restrict__ Ws1,
    const float* __restrict__ Wf2, const float* __restrict__ Ws2,
    uint4* __restrict__ WpkNT, uint4* __restrict__ WpkE)
{
    const int layer = blockIdx.y;
    const float* Wf = layer ? Wf2 : Wf1;
    const float* Ws = layer ? Ws2 : Ws1;
    const int i = blockIdx.x * 256 + threadIdx.x;   // 0..1279
    if (i < 1024) {
        const int p    = i >> 9;
        const int cbi  = (i >> 6) & 7;
        const int l    = i & 63;
        const int n16  = l & 15, quad = l >> 4, kc = quad * 8;
        const int col  = cbi * 16 + n16;
        const int j    = col >> 1;
        const float* Wsel = (col & 1) ? Ws : Wf;
        const int rbase = p * 64;
        U4 b0, b1;
#pragma unroll
        for (int pp = 0; pp < 4; ++pp) {
            b0.u[pp] = pk_bf16(Wsel[(rbase + kc + 2 * pp) * 64 + j],
                               Wsel[(rbase + kc + 2 * pp + 1) * 64 + j]);
            b1.u[pp] = pk_bf16(Wsel[(rbase + 32 + kc + 2 * pp) * 64 + j],
                               Wsel[(rbase + 32 + kc + 2 * pp + 1) * 64 + j]);
        }
        uint4* o = WpkNT + ((size_t)layer * 1024 + i) * 2;
        o[0] = b0.v; o[1] = b1.v;
    } else if (i < 1280) {
        const int k  = i - 1024;
        const int jb = k >> 6;
        const int l  = k & 63;
        const int n16 = l & 15, quad = l >> 4, c0 = quad * 8;
        const int j = jb * 16 + n16;             // contiguous-flush map
        U4 bf_, bs_;
#pragma unroll
        for (int pp = 0; pp < 4; ++pp) {
            bf_.u[pp] = pk_bf16(Wf[(128 + c0 + 2 * pp) * 64 + j],
                                Wf[(128 + c0 + 2 * pp + 1) * 64 + j]);
            bs_.u[pp] = pk_bf16(Ws[(128 + c0 + 2 * pp) * 64 + j],
                                Ws[(128 + c0 + 2 * pp + 1) * 64 + j]);
        }
        uint4* o = WpkE + ((size_t)layer * 256 + k) * 2;
        o[0] = bf_.v; o[1] = bs_.v;
    }
}

// ---- FUSED: scatter_pack (blocks 0..3124) + node_transform L1 (rest) ------
__global__ __launch_bounds__(256) void fused_scatter_nt(
    // scatter args
    const int* __restrict__ ei, const int* __restrict__ off,
    int* __restrict__ cnt, const float* __restrict__ ea,
    unsigned short* __restrict__ eaS, int2* __restrict__ sd_sorted,
    // NT args (layer 1)
    const float* __restrict__ H,
    const float* __restrict__ bf, const float* __restrict__ bs,
    const uint4* __restrict__ Wpk,
    unsigned short* __restrict__ Tdst, unsigned short* __restrict__ Tsrc,
    float* __restrict__ hinit)
{
    __shared__ unsigned short lt[4][16 * NSTR];

    if (blockIdx.x < NB_SCAT) {
        // ---------------- scatter_pack path ----------------
        int e = blockIdx.x * 256 + threadIdx.x;
        int s = ei[e];
        int d = ei[N_EDGES + e];
        int r = atomicAdd(&cnt[d], 1);
        int pos = off[d] + r;
        sd_sorted[pos] = make_int2(s, d);

        const float4* src4 = (const float4*)(ea + (size_t)e * 32);
        uint4* dst16 = (uint4*)(eaS + (size_t)pos * 32);
#pragma unroll
        for (int q = 0; q < 2; ++q) {
            float4 v0 = src4[4 * q + 0];
            float4 v1 = src4[4 * q + 1];
            float4 v2 = src4[4 * q + 2];
            float4 v3 = src4[4 * q + 3];
            uint4 o0;
            o0.x = pk_bf16(v0.x, v0.y); o0.y = pk_bf16(v0.z, v0.w);
            o0.z = pk_bf16(v1.x, v1.y); o0.w = pk_bf16(v1.z, v1.w);
            uint4 o1;
            o1.x = pk_bf16(v2.x, v2.y); o1.y = pk_bf16(v2.z, v2.w);
            o1.z = pk_bf16(v3.x, v3.y); o1.w = pk_bf16(v3.z, v3.w);
            dst16[2 * q + 0] = o0;
            dst16[2 * q + 1] = o1;
        }
        return;
    }

    // ---------------- node_transform path ----------------
    const int lane = threadIdx.x & 63;
    const int wid  = threadIdx.x >> 6;
    const int n16  = lane & 15;
    const int quad = lane >> 4;
    const int kc   = quad * 8;
    unsigned short* L = lt[wid];

    const int gid = (blockIdx.x - NB_SCAT) * 4 + wid;
    const int NW  = (N_NODES / 16) * 2;             // 6250 waves of work
    if (gid >= NW) return;
    const int ntile = gid >> 1;
    const int part  = gid & 1;                      // 0: dst-part, 1: src-part
    unsigned short* Tout = part ? Tsrc : Tdst;

    const float* hrow = H + (size_t)(ntile * 16 + n16) * D;
    float4 q0 = *(const float4*)(hrow + kc);
    float4 q1 = *(const float4*)(hrow + kc + 4);
    float4 q2 = *(const float4*)(hrow + 32 + kc);
    float4 q3 = *(const float4*)(hrow + 32 + kc + 4);
    Frag a0, a1;
    a0.u[0] = pk_bf16(q0.x, q0.y); a0.u[1] = pk_bf16(q0.z, q0.w);
    a0.u[2] = pk_bf16(q1.x, q1.y); a0.u[3] = pk_bf16(q1.z, q1.w);
    a1.u[0] = pk_bf16(q2.x, q2.y); a1.u[1] = pk_bf16(q2.z, q2.w);
    a1.u[2] = pk_bf16(q3.x, q3.y); a1.u[3] = pk_bf16(q3.z, q3.w);

    if (part == 0) {
        float4* hp = (float4*)(hinit + (size_t)(ntile * 16 + n16) * D);
        hp[quad * 2]     = q0;
        hp[quad * 2 + 1] = q1;
        hp[8 + quad * 2] = q2;
        hp[9 + quad * 2] = q3;
    }

#pragma unroll
    for (int cbi = 0; cbi < 8; ++cbi) {
        const int col   = cbi * 16 + n16;
        const int sflag = col & 1;
        const int j     = col >> 1;

        Frag b0, b1;
        {
            const uint4* bp = Wpk + ((size_t)(part * 512 + cbi * 64 + lane)) * 2;
            *(uint4*)&b0 = bp[0];
            *(uint4*)&b1 = bp[1];
        }
        float bias = 0.0f;
        if (part == 0) bias = sflag ? bs[j] : bf[j];

        floatx4 acc = {bias, bias, bias, bias};
        acc = __builtin_amdgcn_mfma_f32_16x16x32_bf16(a0.s, b0.s, acc, 0, 0, 0);
        acc = __builtin_amdgcn_mfma_f32_16x16x32_bf16(a1.s, b1.s, acc, 0, 0, 0);

#pragma unroll
        for (int r = 0; r < 4; ++r)
            L[(quad * 4 + r) * NSTR + col] = bf16_1(acc[r]);
    }

#pragma unroll
    for (int it = 0; it < 4; ++it) {
        const int node_l = it * 4 + quad;
        const int c8     = n16 * 8;
        uint4 v = *(const uint4*)(L + node_l * NSTR + c8);
        *(uint4*)(Tout + (size_t)(ntile * 16 + node_l) * 128 + c8) = v;
    }
}

// ---- node transform (standalone, layer 2) ---------------------------------
__global__ __launch_bounds__(256) void node_transform_mfma(
    const float* __restrict__ H,
    const float* __restrict__ bf,
    const float* __restrict__ bs,
    const uint4* __restrict__ Wpk,
    unsigned short* __restrict__ Tdst,
    unsigned short* __restrict__ Tsrc,
    float* __restrict__ hinit)
{
    __shared__ unsigned short lt[4][16 * NSTR];
    const int lane = threadIdx.x & 63;
    const int wid  = threadIdx.x >> 6;
    const int n16  = lane & 15;
    const int quad = lane >> 4;
    const int kc   = quad * 8;
    unsigned short* L = lt[wid];

    const int gid = blockIdx.x * 4 + wid;
    const int NW  = (N_NODES / 16) * 2;
    if (gid >= NW) return;
    const int ntile = gid >> 1;
    const int part  = gid & 1;
    unsigned short* Tout = part ? Tsrc : Tdst;

    const float* hrow = H + (size_t)(ntile * 16 + n16) * D;
    float4 q0 = *(const float4*)(hrow + kc);
    float4 q1 = *(const float4*)(hrow + kc + 4);
    float4 q2 = *(const float4*)(hrow + 32 + kc);
    float4 q3 = *(const float4*)(hrow + 32 + kc + 4);
    Frag a0, a1;
    a0.u[0] = pk_bf16(q0.x, q0.y); a0.u[1] = pk_bf16(q0.z, q0.w);
    a0.u[2] = pk_bf16(q1.x, q1.y); a0.u[3] = pk_bf16(q1.z, q1.w);
    a1.u[0] = pk_bf16(q2.x, q2.y); a1.u[1] = pk_bf16(q2.z, q2.w);
    a1.u[2] = pk_bf16(q3.x, q3.y); a1.u[3] = pk_bf16(q3.z, q3.w);

    if (part == 0) {
        float4* hp = (float4*)(hinit + (size_t)(ntile * 16 + n16) * D);
        hp[quad * 2]     = q0;
        hp[quad * 2 + 1] = q1;
        hp[8 + quad * 2] = q2;
        hp[9 + quad * 2] = q3;
    }

#pragma unroll
    for (int cbi = 0; cbi < 8; ++cbi) {
        const int col   = cbi * 16 + n16;
        const int sflag = col & 1;
        const int j     = col >> 1;

        Frag b0, b1;
        {
            const uint4* bp = Wpk + ((size_t)(part * 512 + cbi * 64 + lane)) * 2;
            *(uint4*)&b0 = bp[0];
            *(uint4*)&b1 = bp[1];
        }
        float bias = 0.0f;
        if (part == 0) bias = sflag ? bs[j] : bf[j];

        floatx4 acc = {bias, bias, bias, bias};
        acc = __builtin_amdgcn_mfma_f32_16x16x32_bf16(a0.s, b0.s, acc, 0, 0, 0);
        acc = __builtin_amdgcn_mfma_f32_16x16x32_bf16(a1.s, b1.s, acc, 0, 0, 0);

#pragma unroll
        for (int r = 0; r < 4; ++r)
            L[(quad * 4 + r) * NSTR + col] = bf16_1(acc[r]);
    }

#pragma unroll
    for (int it = 0; it < 4; ++it) {
        const int node_l = it * 4 + quad;
        const int c8     = n16 * 8;
        uint4 v = *(const uint4*)(L + node_l * NSTR + c8);
        *(uint4*)(Tout + (size_t)(ntile * 16 + node_l) * 128 + c8) = v;
    }
}

// ---- edge kernel: pipelined per-quad run-length aggregation (R15) ---------
__global__ __launch_bounds__(256) void edge_message_mfma(
    const unsigned short* __restrict__ Tdst,  // [N_NODES][128] bf16
    const unsigned short* __restrict__ Tsrc,  // [N_NODES][128] bf16
    const unsigned short* __restrict__ eaS,   // [N_EDGES][32] bf16, sorted
    const int2* __restrict__ sd_sorted,       // [N_EDGES] (src,dst) sorted
    const uint4* __restrict__ WpkE,           // this layer's edge fragments
    float* __restrict__ hout)                 // [N_NODES][64], pre-init = hin
{
    const int lane = threadIdx.x & 63;
    const int wid  = threadIdx.x >> 6;
    const int n16  = lane & 15;
    const int quad = lane >> 4;
    const int c0   = quad * 8;

    Frag bfr[4], bsr[4];
#pragma unroll
    for (int jb = 0; jb < 4; ++jb) {
        *(uint4*)&bfr[jb] = WpkE[((size_t)(jb * 64 + lane)) * 2 + 0];
        *(uint4*)&bsr[jb] = WpkE[((size_t)(jb * 64 + lane)) * 2 + 1];
    }

    // bijective XCD swizzle (nwg = 3125, q = 390, rr = 5)
    const int nwg = gridDim.x;
    const int xcd = blockIdx.x & 7;
    const int idx = blockIdx.x >> 3;
    const int q   = nwg >> 3, rr = nwg & 7;
    const int sb  = (xcd < rr ? xcd * (q + 1) : rr * (q + 1) + (xcd - rr) * q) + idx;
    const int w   = sb * 4 + wid;            // wave slot 0..12499
    const int base = w * 64;                 // first of 64 consecutive edges

    const floatx4 zero = {0.0f, 0.0f, 0.0f, 0.0f};

    // all 4 A fragments upfront
    const unsigned short* aptr =
        eaS + (size_t)(base + (n16 >> 2) * 16 + (n16 & 3)) * 32 + c0;
    Frag af0, af1, af2, af3;
    af0.s = *(const short8*)(aptr);
    af1.s = *(const short8*)(aptr + 128);
    af2.s = *(const short8*)(aptr + 256);
    af3.s = *(const short8*)(aptr + 384);

    // all 16 sd upfront (quad-uniform, 8x int4)
    const int4* sdp4 = (const int4*)(sd_sorted + base + quad * 16);
    int4 sdq[8];
#pragma unroll
    for (int i = 0; i < 8; ++i) sdq[i] = sdp4[i];

#define SV(e) ((((e) & 1) != 0) ? sdq[(e) >> 1].z : sdq[(e) >> 1].x)
#define DV(e) ((((e) & 1) != 0) ? sdq[(e) >> 1].w : sdq[(e) >> 1].y)

    // per-quad run-length state (channel jb*16+n16 in acc_jb)
    int cur_d = -1;
    unsigned dr0 = 0, dr1 = 0, dr2 = 0, dr3 = 0;
    float acc0 = 0.f, acc1 = 0.f, acc2 = 0.f, acc3 = 0.f;

#pragma unroll
    for (int tt = 0; tt < 4; ++tt) {
        // hoisted src-row loads for this tt's 4 edges (latency hides
        // under the MFMAs below + previous activations)
        unsigned s0[4], s1[4], s2[4], s3[4];
#pragma unroll
        for (int r = 0; r < 4; ++r) {
            const unsigned* srow =
                (const unsigned*)(Tsrc + (size_t)SV(4 * tt + r) * 128);
            s0[r] = srow[n16];
            s1[r] = srow[16 + n16];
            s2[r] = srow[32 + n16];
            s3[r] = srow[48 + n16];
        }

        const Frag& af = (tt == 0) ? af0 : (tt == 1) ? af1 : (tt == 2) ? af2 : af3;
        floatx4 accf[4], accs[4];
#pragma unroll
        for (int jb = 0; jb < 4; ++jb) {
            accf[jb] = __builtin_amdgcn_mfma_f32_16x16x32_bf16(af.s, bfr[jb].s, zero, 0, 0, 0);
            accs[jb] = __builtin_amdgcn_mfma_f32_16x16x32_bf16(af.s, bsr[jb].s, zero, 0, 0, 0);
        }

#pragma unroll
        for (int r = 0; r < 4; ++r) {
            const int dv = DV(4 * tt + r);
            if (dv != cur_d) {
                if (cur_d >= 0) {
                    float* hp = hout + (size_t)cur_d * D + n16;
                    atomicAdd(hp +  0, acc0);     // 16 lanes x contiguous 64B
                    atomicAdd(hp + 16, acc1);
                    atomicAdd(hp + 32, acc2);
                    atomicAdd(hp + 48, acc3);
                }
                cur_d = dv;
                const unsigned* drow = (const unsigned*)(Tdst + (size_t)dv * 128);
                dr0 = drow[n16];
                dr1 = drow[16 + n16];
                dr2 = drow[32 + n16];
                dr3 = drow[48 + n16];
                acc0 = acc1 = acc2 = acc3 = 0.f;
            }
#pragma unroll
            for (int jb = 0; jb < 4; ++jb) {
                unsigned d2 = (jb == 0) ? dr0 : (jb == 1) ? dr1 : (jb == 2) ? dr2 : dr3;
                unsigned sv = (jb == 0) ? s0[r] : (jb == 1) ? s1[r] : (jb == 2) ? s2[r] : s3[r];
                float vf = accf[jb][r] + upk(d2 & 0xFFFFu) + upk(sv & 0xFFFFu);
                float vs = accs[jb][r] + upk(d2 >> 16) + upk(sv >> 16);
                float sig = __builtin_amdgcn_rcpf(1.0f + __expf(-vf));
                float spl = fmaxf(vs, 0.0f) + __logf(1.0f + __expf(-fabsf(vs)));
                float msg = sig * spl;
                if      (jb == 0) acc0 += msg;
                else if (jb == 1) acc1 += msg;
                else if (jb == 2) acc2 += msg;
                else              acc3 += msg;
            }
        }
    }
#undef SV
#undef DV
    // final flush (cur_d always valid here)
    {
        float* hp = hout + (size_t)cur_d * D + n16;
        atomicAdd(hp +  0, acc0);
        atomicAdd(hp + 16, acc1);
        atomicAdd(hp + 32, acc2);
        atomicAdd(hp + 48, acc3);
    }
}

// segment_sum(h, batch) into pooled[N_GRAPHS][64]
__global__ __launch_bounds__(256) void pool_kernel(
    const float* __restrict__ h,
    const int* __restrict__ batch,
    float* __restrict__ pooled)
{
    const int lane = threadIdx.x & 63;
    const int wid  = threadIdx.x >> 6;
    const int w = blockIdx.x * 4 + wid;
    const int n0 = w * 16;
    if (n0 >= N_NODES) return;
    const int nend = (n0 + 16 < N_NODES) ? (n0 + 16) : N_NODES;

    int cur = batch[n0];
    float acc = 0.0f;
    for (int n = n0; n < nend; ++n) {
        int b = batch[n];                      // wave-uniform scalar load
        float v = h[(size_t)n * D + lane];
        if (b != cur) {
            atomicAdd(&pooled[(size_t)cur * D + lane], acc);
            cur = b; acc = v;
        } else {
            acc += v;
        }
    }
    atomicAdd(&pooled[(size_t)cur * D + lane], acc);
}

__global__ __launch_bounds__(256) void out_kernel(
    const float* __restrict__ pooled,
    const float* __restrict__ Wout,
    const float* __restrict__ bout,
    float* __restrict__ out)
{
    const int g = blockIdx.x * blockDim.x + threadIdx.x;
    if (g >= N_GRAPHS) return;
    float acc = bout[0];
#pragma unroll
    for (int j = 0; j < D; ++j) acc = fmaf(pooled[(size_t)g * D + j], Wout[j], acc);
    out[g] = acc;
}

extern "C" void kernel_launch(void* const* d_in, const int* in_sizes, int n_in,
                              void* d_out, int out_size, void* d_ws, size_t ws_size,
                              hipStream_t stream) {
    const float* x     = (const float*)d_in[0];
    const int*   ei    = (const int*)  d_in[1];
    const float* ea    = (const float*)d_in[2];
    const int*   batch = (const int*)  d_in[3];
    const float* Wf1   = (const float*)d_in[4];
    const float* bf1   = (const float*)d_in[5];
    const float* Ws1   = (const float*)d_in[6];
    const float* bs1   = (const float*)d_in[7];
    const float* Wf2   = (const float*)d_in[8];
    const float* bf2   = (const float*)d_in[9];
    const float* Ws2   = (const float*)d_in[10];
    const float* bs2   = (const float*)d_in[11];
    const float* Wout  = (const float*)d_in[12];
    const float* bout  = (const float*)d_in[13];
    float* out = (float*)d_out;

    // workspace carve (~110 MB)
    char* base = (char*)d_ws;
    size_t o = 0;
    unsigned short* Tdst = (unsigned short*)(base + o); o += (size_t)N_NODES * 128 * 2;
    unsigned short* Tsrc = (unsigned short*)(base + o); o += (size_t)N_NODES * 128 * 2;
    unsigned short* eaS  = (unsigned short*)(base + o); o += (size_t)N_EDGES * 32 * 2;
    float* h1     = (float*)(base + o); o += (size_t)N_NODES * D * 4;
    float* h2     = (float*)(base + o); o += (size_t)N_NODES * D * 4;
    float* pooled = (float*)(base + o); o += (size_t)N_GRAPHS * D * 4;
    int* deg  = (int*)(base + o); o += (size_t)N_NODES * 4;
    int* off  = (int*)(base + o); o += (size_t)(N_NODES + 1) * 4;
    int* tsum = (int*)(base + o); o += 256 * 4;
    int2* sd_sorted = (int2*)(base + o); o += (size_t)N_EDGES * 8;
    uint4* WpkNT = (uint4*)(base + o); o += (size_t)2 * 1024 * 2 * 16;
    uint4* WpkE  = (uint4*)(base + o); o += (size_t)2 * 256 * 2 * 16;

    // ---- W fragment pack (both layers, both layouts) ----
    pack_W<<<dim3(5, 2), 256, 0, stream>>>(Wf1, Ws1, Wf2, Ws2, WpkNT, WpkE);

    // ---- CSR build ----
    hipMemsetAsync(deg, 0, (size_t)N_NODES * 4, stream);
    hist_kernel<<<N_EDGES / 256, 256, 0, stream>>>(ei, deg);
    scan1<<<NB_SCAN, 256, 0, stream>>>(deg, off, tsum);
    scan2<<<1, 256, 0, stream>>>(tsum);
    scan3<<<NB_SCAN, 256, 0, stream>>>(off, tsum);
    hipMemsetAsync(deg, 0, (size_t)N_NODES * 4, stream);

    // ---- fused scatter_pack + node_transform L1 (independent work) ----
    fused_scatter_nt<<<NB_SCAT + NB_NT, 256, 0, stream>>>(
        ei, off, deg, ea, eaS, sd_sorted,
        x, bf1, bs1, WpkNT, Tdst, Tsrc, h1);

    // ---- layer 1 edge ----
    edge_message_mfma<<<3125, 256, 0, stream>>>(Tdst, Tsrc, eaS, sd_sorted,
                                                WpkE, h1);

    // ---- layer 2 ----  (node_transform also writes h2 = h1)
    node_transform_mfma<<<1563, 256, 0, stream>>>(h1, bf2, bs2, WpkNT + 2048, Tdst, Tsrc, h2);
    edge_message_mfma<<<3125, 256, 0, stream>>>(Tdst, Tsrc, eaS, sd_sorted,
                                                WpkE + 512, h2);

    // ---- pool + out ----
    hipMemsetAsync(pooled, 0, (size_t)N_GRAPHS * D * 4, stream);
    pool_kernel<<<782, 256, 0, stream>>>(h2, batch, pooled);
    out_kernel<<<2, 256, 0, stream>>>(pooled, Wout, bout, out);
}